// Round 15
// baseline (123.456 us; speedup 1.0000x reference)
//
#include <hip/hip_runtime.h>
#include <math.h>
#include <stdint.h>

// B=2, S=4096, H=4, D=32, C=64. SCALE=16 folded as 16*log2(e) into q (base-2 softmax).
//
// ws layout (bytes), total ~18.3 MB:
//   0    : qf raw fp32 [8][4096][32]
//   4 MB : kf raw fp32 [8][4096][32]
//   8 MB : kfr_hi ushort frag-major [8][128 jt][2 c][64 lane][8]   (sigma rows)
//   10 MB: kfr_lo ushort frag-major
//   12 MB: vfr    ushort frag-major [8][128 jt][2 c][64 lane][8]
//   14 MB: (qfr_hi unused since R14)
//   16 MB: (qfr_lo unused since R14)
//   18 MB: psum fp32 (128 KB), psq (128 KB)
//
// R4: qkv on MFMA (split-precision bf16 hh+hl+lh, ~2^-16 rel).
// R7: proj fused into attn epilogue (atomicAdd partials, qkv bias-inits out).
// R9: attn = 2 i-tiles/wave, 4 waves/block, grid 512 (best attn: ~55us; fatter
//     waves lose — R12 dual-j ILP regressed to 62; TLP > hand-woven ILP).
// R13 LESSON: norm grid 4x was neutral — duplicated stats reduce ate the gain.
// R14: Q-norm FUSED into attn prologue (per-block stats reduce + in-register
//     frag build from raw qf; kills 8MB qfr round-trip); norm is K-ONLY grid 128.

typedef __attribute__((ext_vector_type(8))) short short8;
typedef __attribute__((ext_vector_type(2))) float f32x2;
typedef __attribute__((ext_vector_type(4))) float f32x4;
typedef __attribute__((ext_vector_type(16))) float f32x16;

#define QSCALE 23.083120654223414f /* 16 * log2(e) */

#if __has_builtin(__builtin_amdgcn_exp2f)
#define EXP2F(x) __builtin_amdgcn_exp2f(x)
#else
#define EXP2F(x) exp2f(x)
#endif

__device__ inline uint32_t pack_hilo(float y) {
  uint32_t uy = __float_as_uint(y);
  uint32_t hb = (uy + 0x7fffu + ((uy >> 16) & 1u)) >> 16;  // RNE bf16
  float hf = __uint_as_float(hb << 16);
  float r = y - hf;
  uint32_t ur = __float_as_uint(r);
  uint32_t lb = (ur + 0x7fffu + ((ur >> 16) & 1u)) >> 16;
  return (hb << 16) | (lb & 0xffffu);
}

__device__ inline ushort f32_to_bf16(float y) {
  uint32_t uy = __float_as_uint(y);
  return (ushort)((uy + 0x7fffu + ((uy >> 16) & 1u)) >> 16);
}

__device__ inline float bpermf(int addr, float v) {
  return __int_as_float(__builtin_amdgcn_ds_bpermute(addr, __float_as_int(v)));
}

__device__ inline short8 as_s8(uint4 v) {
  union { uint4 u; short8 s; } t;
  t.u = v;
  return t.s;
}

// ---------------------------------------------------------------------------
// Kernel 1 (R4): qkv = input @ w_qkv via 32x32x16 bf16 MFMA, split precision.
// R7: also pre-fills out with bias (attn atomically accumulates proj partials).
__global__ __launch_bounds__(256) void qkv_kernel(const float* __restrict__ in,
                                                  const float* __restrict__ w,
                                                  float* __restrict__ qf,
                                                  float* __restrict__ kf,
                                                  ushort* __restrict__ vfr,
                                                  float* __restrict__ psum,
                                                  float* __restrict__ psq,
                                                  const float* __restrict__ bias,
                                                  float* __restrict__ out) {
  __shared__ char smem[18432];  // Bh[64*72]u16 | Bl[64*72]u16; VT[64][68]f32 aliases after
  __shared__ float ssum[64], ssq[64];
  ushort* Bh = (ushort*)smem;
  ushort* Bl = (ushort*)(smem + 9216);
  float* VT = (float*)smem;  // 64*68*4 = 17408 <= 18432; used only after barrier

  const int ctile = blockIdx.x % 6;
  const int stile = blockIdx.x / 6;
  const int tid = threadIdx.x;
  const int row0 = stile * 64;
  const int sel = ctile >> 1;  // 0=q 1=k 2=v  (block-uniform)

  // bias-init of out (proj accumulator target); grid-stride, 8192*64 floats
  for (int i = blockIdx.x * 256 + tid; i < 8192 * 64; i += 768 * 256)
    out[i] = bias[i & 63];

  if (tid < 64) { ssum[tid] = 0.f; ssq[tid] = 0.f; }

  // ---- stage w^T hi/lo: thread: col = tid&63, k = (tid>>6)*16 .. +15
  {
    const int col = tid & 63;
    const int k0 = (tid >> 6) * 16;
    const float* wp = w + (size_t)k0 * 384 + ctile * 64 + col;
    float xv[16];
#pragma unroll
    for (int j = 0; j < 16; ++j) xv[j] = wp[(size_t)j * 384];
    uint32_t hi[8], lo[8];
#pragma unroll
    for (int p = 0; p < 8; ++p) {
      const uint32_t u0 = __float_as_uint(xv[2 * p]);
      const uint32_t u1 = __float_as_uint(xv[2 * p + 1]);
      hi[p] = __builtin_amdgcn_perm(u1, u0, 0x07060302u);
      const float d0 = xv[2 * p] - __uint_as_float(u0 & 0xffff0000u);
      const float d1 = xv[2 * p + 1] - __uint_as_float(u1 & 0xffff0000u);
      lo[p] = __builtin_amdgcn_perm(__float_as_uint(d1), __float_as_uint(d0), 0x07060302u);
    }
    uint4* bh = (uint4*)&Bh[col * 72 + k0];
    bh[0] = make_uint4(hi[0], hi[1], hi[2], hi[3]);
    bh[1] = make_uint4(hi[4], hi[5], hi[6], hi[7]);
    uint4* bl = (uint4*)&Bl[col * 72 + k0];
    bl[0] = make_uint4(lo[0], lo[1], lo[2], lo[3]);
    bl[1] = make_uint4(lo[4], lo[5], lo[6], lo[7]);
  }
  __syncthreads();

  const int wv = tid >> 6, lane = tid & 63;
  const int wr = wv >> 1, wc = wv & 1;
  const int h2 = lane >> 5, pl = lane & 31;

  // ---- A frags from global (in rows), trunc hi/lo
  short8 ah[4], al[4];
  {
    const float* ap = in + (size_t)(row0 + wr * 32 + pl) * 64 + h2 * 8;
#pragma unroll
    for (int kb = 0; kb < 4; ++kb) {
      const float4 xa = *(const float4*)(ap + kb * 16);
      const float4 xb = *(const float4*)(ap + kb * 16 + 4);
      const float xs[8] = {xa.x, xa.y, xa.z, xa.w, xb.x, xb.y, xb.z, xb.w};
      uint32_t hp[4], lp[4];
#pragma unroll
      for (int p = 0; p < 4; ++p) {
        const uint32_t u0 = __float_as_uint(xs[2 * p]);
        const uint32_t u1 = __float_as_uint(xs[2 * p + 1]);
        hp[p] = __builtin_amdgcn_perm(u1, u0, 0x07060302u);
        const float d0 = xs[2 * p] - __uint_as_float(u0 & 0xffff0000u);
        const float d1 = xs[2 * p + 1] - __uint_as_float(u1 & 0xffff0000u);
        lp[p] = __builtin_amdgcn_perm(__float_as_uint(d1), __float_as_uint(d0), 0x07060302u);
      }
      union { uint32_t u[4]; short8 s; } th, tl;
      th.u[0] = hp[0]; th.u[1] = hp[1]; th.u[2] = hp[2]; th.u[3] = hp[3];
      tl.u[0] = lp[0]; tl.u[1] = lp[1]; tl.u[2] = lp[2]; tl.u[3] = lp[3];
      ah[kb] = th.s;
      al[kb] = tl.s;
    }
  }

  // ---- B frags from LDS
  const ushort* bhp = &Bh[(wc * 32 + pl) * 72 + h2 * 8];
  const ushort* blp = &Bl[(wc * 32 + pl) * 72 + h2 * 8];
  f32x16 acc = {};
#pragma unroll
  for (int kb = 0; kb < 4; ++kb) {
    const short8 bh = *(const short8*)(bhp + kb * 16);
    const short8 bl = *(const short8*)(blp + kb * 16);
    acc = __builtin_amdgcn_mfma_f32_32x32x16_bf16(ah[kb], bh, acc, 0, 0, 0);
    acc = __builtin_amdgcn_mfma_f32_32x32x16_bf16(ah[kb], bl, acc, 0, 0, 0);
    acc = __builtin_amdgcn_mfma_f32_32x32x16_bf16(al[kb], bh, acc, 0, 0, 0);
  }

  const int b = row0 >> 12;
  const int sl0 = (row0 & 4095) + wr * 32;
  const int chg = ctile * 64 + wc * 32 + pl;

  if (sel < 2) {
    const int hd0 = chg & 127;
    const int h = hd0 >> 5, d0 = hd0 & 31;
    float* dst = (sel == 0 ? qf : kf) + ((size_t)(b * 4 + h) * 4096 + sl0) * 32 + d0;
    float s1 = 0.f, s2 = 0.f;
#pragma unroll
    for (int reg = 0; reg < 16; ++reg) {
      const int r = (reg & 3) + 8 * (reg >> 2) + 4 * h2;
      dst[(size_t)r * 32] = acc[reg];
      s1 += acc[reg];
      s2 += acc[reg] * acc[reg];
    }
    atomicAdd(&ssum[wc * 32 + pl], s1);
    atomicAdd(&ssq[wc * 32 + pl], s2);
    __syncthreads();
    if (tid < 64) {
      const int ch = (ctile & 1) * 64 + tid;
      const int idx = (((sel * 2 + b) * 128) + ch) * 64 + (stile & 63);
      psum[idx] = ssum[tid];
      psq[idx] = ssq[tid];
    }
  } else {
    // v: acc (C-layout) -> VT[ch 64][68 s] fp32 (aliases dead w-LDS), then pack.
    __syncthreads();  // all waves done reading Bh/Bl
    const int chv = wc * 32 + pl;
#pragma unroll
    for (int reg = 0; reg < 16; ++reg) {
      const int r = wr * 32 + (reg & 3) + 8 * (reg >> 2) + 4 * h2;
      VT[chv * 68 + r] = acc[reg];
    }
    __syncthreads();
    const int jt0 = (row0 & 4095) >> 5;
#pragma unroll
    for (int hl = 0; hl < 2; ++hl) {
      const int jtl = tid >> 7, c = (tid >> 6) & 1, ln = tid & 63;
      const int d = ln & 31, hh = ln >> 5;
      const int jloc = 32 * jtl + 16 * c + 8 * hh;
      const int ch = hl * 32 + d;
      const float4 f0 = *(const float4*)&VT[ch * 68 + jloc];
      const float4 f1 = *(const float4*)&VT[ch * 68 + jloc + 4];
      uint4 pk;
      pk.x = (uint32_t)f32_to_bf16(f0.x) | ((uint32_t)f32_to_bf16(f0.y) << 16);
      pk.y = (uint32_t)f32_to_bf16(f0.z) | ((uint32_t)f32_to_bf16(f0.w) << 16);
      pk.z = (uint32_t)f32_to_bf16(f1.x) | ((uint32_t)f32_to_bf16(f1.y) << 16);
      pk.w = (uint32_t)f32_to_bf16(f1.z) | ((uint32_t)f32_to_bf16(f1.w) << 16);
      const int h = (ctile - 4) * 2 + hl;
      ushort* dst =
          vfr + (((size_t)((b * 4 + h) * 128 + jt0 + jtl) * 2 + c) * 64 + ln) * 8;
      *(uint4*)dst = pk;
    }
  }
}

// ---------------------------------------------------------------------------
// Kernel 2 (R14): K-ONLY stats + pack into kfr hi/lo (sigma rows). grid 128:
// bh = bx>>4, s0 = (bx&15)*256. (Q path moved into attn prologue.)
__global__ __launch_bounds__(256) void norm_kernel(const float* __restrict__ kf,
                                                   ushort* __restrict__ kfr_hi,
                                                   ushort* __restrict__ kfr_lo,
                                                   const float* __restrict__ psum,
                                                   const float* __restrict__ psq) {
  const int bx = blockIdx.x;
  const int bh = bx >> 4;
  const int s0 = (bx & 15) * 256;
  const int tid = threadIdx.x;
  __shared__ float red[2][32][8];
  __shared__ float tA[32], tB[32];
  {
    const int d = tid >> 3, p = tid & 7;
    const int base = ((2 + (bh >> 2)) * 128 + (bh & 3) * 32 + d) * 64 + p * 8;
    float sm = 0.f, sq = 0.f;
#pragma unroll
    for (int e = 0; e < 8; ++e) {
      sm += psum[base + e];
      sq += psq[base + e];
    }
    red[0][d][p] = sm;
    red[1][d][p] = sq;
  }
  __syncthreads();
  if (tid < 32) {
    float sm = 0.f, sq = 0.f;
#pragma unroll
    for (int e = 0; e < 8; ++e) {
      sm += red[0][tid][e];
      sq += red[1][tid][e];
    }
    const float mu = sm * (1.f / 4096.f);
    const float inv = rsqrtf(sq * (1.f / 4096.f) - mu * mu + 1e-5f);
    tA[tid] = inv;
    tB[tid] = -mu * inv;
  }
  __syncthreads();

  const float* src = kf + (size_t)bh * 4096 * 32;
  ushort* dhi = kfr_hi + (size_t)(bh * 128 + (s0 >> 5)) * 1024;
  ushort* dlo = kfr_lo + (size_t)(bh * 128 + (s0 >> 5)) * 1024;
#pragma unroll
  for (int pass = 0; pass < 4; ++pass) {
    const int idx = tid + pass * 256;
    const int jtl = idx >> 7;
    const int c = (idx >> 6) & 1;
    const int ln = idx & 63;
    const int p = ln & 31, hh = ln >> 5;
    const int row = (p & 0x13) | ((p & 4) << 1) | ((p & 8) >> 1);  // sigma swap23
    const int s = s0 + 32 * jtl + row;
    const int d0 = 16 * c + 8 * hh;
    const float4 x0 = *(const float4*)&src[(size_t)s * 32 + d0];
    const float4 x1 = *(const float4*)&src[(size_t)s * 32 + d0 + 4];
    const float4 A0 = *(const float4*)&tA[d0];
    const float4 A1 = *(const float4*)&tA[d0 + 4];
    const float4 B0 = *(const float4*)&tB[d0];
    const float4 B1 = *(const float4*)&tB[d0 + 4];
    uint32_t pk[8];
    pk[0] = pack_hilo(fmaf(x0.x, A0.x, B0.x));
    pk[1] = pack_hilo(fmaf(x0.y, A0.y, B0.y));
    pk[2] = pack_hilo(fmaf(x0.z, A0.z, B0.z));
    pk[3] = pack_hilo(fmaf(x0.w, A0.w, B0.w));
    pk[4] = pack_hilo(fmaf(x1.x, A1.x, B1.x));
    pk[5] = pack_hilo(fmaf(x1.y, A1.y, B1.y));
    pk[6] = pack_hilo(fmaf(x1.z, A1.z, B1.z));
    pk[7] = pack_hilo(fmaf(x1.w, A1.w, B1.w));
    uint4 HV, LV;
    HV.x = __builtin_amdgcn_perm(pk[1], pk[0], 0x07060302u);
    HV.y = __builtin_amdgcn_perm(pk[3], pk[2], 0x07060302u);
    HV.z = __builtin_amdgcn_perm(pk[5], pk[4], 0x07060302u);
    HV.w = __builtin_amdgcn_perm(pk[7], pk[6], 0x07060302u);
    LV.x = __builtin_amdgcn_perm(pk[1], pk[0], 0x05040100u);
    LV.y = __builtin_amdgcn_perm(pk[3], pk[2], 0x05040100u);
    LV.z = __builtin_amdgcn_perm(pk[5], pk[4], 0x05040100u);
    LV.w = __builtin_amdgcn_perm(pk[7], pk[6], 0x05040100u);
    const size_t doff = ((size_t)(jtl * 2 + c) * 64 + ln) * 8;
    *(uint4*)(dhi + doff) = HV;
    *(uint4*)(dlo + doff) = LV;
  }
}

// ---------------------------------------------------------------------------
// Kernel 3 (R14): flash attention (2 i-tiles/wave) + Q-norm prologue + fused
// output projection. grid 512 (bh = bx&7, itp = bx>>3); block 256 = 4 waves.
// Prologue: per-block Q stats (psum/psq reduce, ML as scratch) -> tA/tB ->
// in-register Q frag build from raw qf (pack_hilo, bit-identical to old norm).
__global__ __launch_bounds__(256, 2) void attn_kernel(const float* __restrict__ qf,
                                                      const float* __restrict__ psum,
                                                      const float* __restrict__ psq,
                                                      const ushort* __restrict__ kfr_hi,
                                                      const ushort* __restrict__ kfr_lo,
                                                      const ushort* __restrict__ vfr,
                                                      const float* __restrict__ wout,
                                                      float* __restrict__ out) {
  __shared__ float OM[4 * 2 * 32 * 36];  // [wave][itl][i 32][36]; reused by V2/WL
  __shared__ float ML[4 * 2 * 64];       // prologue scratch; later [wave][itl][m|l]
  __shared__ float tAB[64];              // tA[32] | tB[32]

  const int tid = threadIdx.x;
  const int w = tid >> 6;  // js = w, 4 j-splits
  const int lane = tid & 63;
  const int pl = lane & 31, h2 = lane >> 5;
  const int bh = blockIdx.x & 7;
  const int itp = blockIdx.x >> 3;

  // ---- Q-norm prologue: stats for this bh (tensor=0)
  {
    const int d = tid >> 3, p = tid & 7;
    const int base = ((bh >> 2) * 128 + (bh & 3) * 32 + d) * 64 + p * 8;
    float sm = 0.f, sq = 0.f;
#pragma unroll
    for (int e = 0; e < 8; ++e) {
      sm += psum[base + e];
      sq += psq[base + e];
    }
    ML[d * 8 + p] = sm;
    ML[256 + d * 8 + p] = sq;
  }
  __syncthreads();
  if (tid < 32) {
    float sm = 0.f, sq = 0.f;
#pragma unroll
    for (int e = 0; e < 8; ++e) {
      sm += ML[tid * 8 + e];
      sq += ML[256 + tid * 8 + e];
    }
    const float mu = sm * (1.f / 4096.f);
    const float inv = rsqrtf(sq * (1.f / 4096.f) - mu * mu + 1e-5f) * QSCALE;
    tAB[tid] = inv;
    tAB[32 + tid] = -mu * inv;
  }
  __syncthreads();

  // ---- build Q frags in-register from raw qf (both i-tiles, both c-halves)
  short8 qfrag_h[2][2], qfrag_l[2][2];  // [itl][c]
  {
    const float* qsrc = qf + (size_t)bh * 4096 * 32;
#pragma unroll
    for (int itl = 0; itl < 2; ++itl) {
      const int s = (itp * 2 + itl) * 32 + pl;
#pragma unroll
      for (int c = 0; c < 2; ++c) {
        const int d0 = 16 * c + 8 * h2;
        const float4 x0 = *(const float4*)&qsrc[(size_t)s * 32 + d0];
        const float4 x1 = *(const float4*)&qsrc[(size_t)s * 32 + d0 + 4];
        const float4 A0 = *(const float4*)&tAB[d0];
        const float4 A1 = *(const float4*)&tAB[d0 + 4];
        const float4 B0 = *(const float4*)&tAB[32 + d0];
        const float4 B1 = *(const float4*)&tAB[32 + d0 + 4];
        uint32_t pk[8];
        pk[0] = pack_hilo(fmaf(x0.x, A0.x, B0.x));
        pk[1] = pack_hilo(fmaf(x0.y, A0.y, B0.y));
        pk[2] = pack_hilo(fmaf(x0.z, A0.z, B0.z));
        pk[3] = pack_hilo(fmaf(x0.w, A0.w, B0.w));
        pk[4] = pack_hilo(fmaf(x1.x, A1.x, B1.x));
        pk[5] = pack_hilo(fmaf(x1.y, A1.y, B1.y));
        pk[6] = pack_hilo(fmaf(x1.z, A1.z, B1.z));
        pk[7] = pack_hilo(fmaf(x1.w, A1.w, B1.w));
        union { uint32_t u[4]; short8 s8; } hv, lv;
        hv.u[0] = __builtin_amdgcn_perm(pk[1], pk[0], 0x07060302u);
        hv.u[1] = __builtin_amdgcn_perm(pk[3], pk[2], 0x07060302u);
        hv.u[2] = __builtin_amdgcn_perm(pk[5], pk[4], 0x07060302u);
        hv.u[3] = __builtin_amdgcn_perm(pk[7], pk[6], 0x07060302u);
        lv.u[0] = __builtin_amdgcn_perm(pk[1], pk[0], 0x05040100u);
        lv.u[1] = __builtin_amdgcn_perm(pk[3], pk[2], 0x05040100u);
        lv.u[2] = __builtin_amdgcn_perm(pk[5], pk[4], 0x05040100u);
        lv.u[3] = __builtin_amdgcn_perm(pk[7], pk[6], 0x05040100u);
        qfrag_h[itl][c] = hv.s8;
        qfrag_l[itl][c] = lv.s8;
      }
    }
  }
  __syncthreads();  // ML scratch reads done; main loop may now leave ML alone

  const short8 qh0_0 = qfrag_h[0][0], qh1_0 = qfrag_h[0][1];
  const short8 ql0_0 = qfrag_l[0][0], ql1_0 = qfrag_l[0][1];
  const short8 qh0_1 = qfrag_h[1][0], qh1_1 = qfrag_h[1][1];
  const short8 ql0_1 = qfrag_l[1][0], ql1_1 = qfrag_l[1][1];

  const int bp32 = (lane ^ 32) << 2;

  const size_t kbase = (size_t)(bh * 128 + w * 32) * 1024 + lane * 8;
  const ushort* kh = kfr_hi + kbase;
  const ushort* kl = kfr_lo + kbase;
  const ushort* vp = vfr + kbase;

  union { f32x16 v; f32x2 p[8]; } oac0, oac1;
#pragma unroll
  for (int r = 0; r < 16; ++r) { oac0.v[r] = 0.f; oac1.v[r] = 0.f; }
  const f32x16 zf = {};  // persistent zero C operand
  float m0 = -INFINITY, l0 = 0.f, m1 = -INFINITY, l1 = 0.f;

  uint4 rk0 = *(const uint4*)(kh);
  uint4 rk1 = *(const uint4*)(kh + 512);
  uint4 rl0 = *(const uint4*)(kl);
  uint4 rl1 = *(const uint4*)(kl + 512);

  for (int t = 0; t < 32; ++t) {
    const short8 ck0 = as_s8(rk0), ck1 = as_s8(rk1);
    const short8 cl0 = as_s8(rl0), cl1 = as_s8(rl1);
    // V direct load for this iter (consumed at PV, ~400cy later)
    const uint4 rv0 = *(const uint4*)(vp + t * 1024);
    const uint4 rv1 = *(const uint4*)(vp + t * 1024 + 512);
    {  // K prefetch t+1 (last iter reads in-bounds adjacent ws region, unused)
      const int off = (t + 1) * 1024;
      rk0 = *(const uint4*)(kh + off);
      rk1 = *(const uint4*)(kh + off + 512);
      rl0 = *(const uint4*)(kl + off);
      rl1 = *(const uint4*)(kl + off + 512);
    }
    const short8 cv0 = as_s8(rv0), cv1 = as_s8(rv1);

#pragma unroll
    for (int itl = 0; itl < 2; ++itl) {
      const short8 qh0 = itl == 0 ? qh0_0 : qh0_1;
      const short8 qh1 = itl == 0 ? qh1_0 : qh1_1;
      const short8 ql0 = itl == 0 ? ql0_0 : ql0_1;
      const short8 ql1 = itl == 0 ? ql1_0 : ql1_1;
      float m = itl == 0 ? m0 : m1;
      float l = itl == 0 ? l0 : l1;

      // --- S^T = K·Q^T (A = K sigma-rows, B = Q), split precision: 6 MFMAs
      __builtin_amdgcn_s_setprio(1);
      union { f32x16 v; f32x2 p[8]; } sc;
      sc.v = __builtin_amdgcn_mfma_f32_32x32x16_bf16(ck0, qh0, zf, 0, 0, 0);
      sc.v = __builtin_amdgcn_mfma_f32_32x32x16_bf16(ck1, qh1, sc.v, 0, 0, 0);
      sc.v = __builtin_amdgcn_mfma_f32_32x32x16_bf16(ck0, ql0, sc.v, 0, 0, 0);
      sc.v = __builtin_amdgcn_mfma_f32_32x32x16_bf16(ck1, ql1, sc.v, 0, 0, 0);
      sc.v = __builtin_amdgcn_mfma_f32_32x32x16_bf16(cl0, qh0, sc.v, 0, 0, 0);
      sc.v = __builtin_amdgcn_mfma_f32_32x32x16_bf16(cl1, qh1, sc.v, 0, 0, 0);
      __builtin_amdgcn_s_setprio(0);

      // --- online softmax (base-2); max via v_max3 tree
      const float x0 = fmaxf(fmaxf(sc.v[0], sc.v[1]), sc.v[2]);
      const float x1 = fmaxf(fmaxf(sc.v[3], sc.v[4]), sc.v[5]);
      const float x2 = fmaxf(fmaxf(sc.v[6], sc.v[7]), sc.v[8]);
      const float x3 = fmaxf(fmaxf(sc.v[9], sc.v[10]), sc.v[11]);
      const float x4 = fmaxf(fmaxf(sc.v[12], sc.v[13]), sc.v[14]);
      float mx = fmaxf(fmaxf(fmaxf(x0, x1), x2), fmaxf(fmaxf(x3, x4), sc.v[15]));
      mx = fmaxf(mx, bpermf(bp32, mx));
      const float mn = fmaxf(m, mx);
      const float al = EXP2F(m - mn);
      m = mn;
      const f32x2 mn2 = {mn, mn};
#pragma unroll
      for (int i = 0; i < 8; ++i) sc.p[i] = sc.p[i] - mn2;
#pragma unroll
      for (int r = 0; r < 16; ++r) sc.v[r] = EXP2F(sc.v[r]);
      const f32x2 a0 = sc.p[0] + sc.p[1], a1 = sc.p[2] + sc.p[3];
      const f32x2 a2 = sc.p[4] + sc.p[5], a3 = sc.p[6] + sc.p[7];
      const f32x2 b0 = a0 + a1, b1 = a2 + a3;
      const f32x2 c0 = b0 + b1;
      float rs = c0.x + c0.y;
      rs += bpermf(bp32, rs);
      l = l * al + rs;
      const f32x2 al2 = {al, al};

      // --- P -> bf16 (truncation; bias comp in merge)
      uint32_t pk[8];
#pragma unroll
      for (int i = 0; i < 8; ++i)
        pk[i] = __builtin_amdgcn_perm(__float_as_uint(sc.v[2 * i + 1]),
                                      __float_as_uint(sc.v[2 * i]), 0x07060302u);
      union { uint32_t u4[4]; short8 s8; } p0, p1;
      p0.u4[0] = pk[0]; p0.u4[1] = pk[1]; p0.u4[2] = pk[2]; p0.u4[3] = pk[3];
      p1.u4[0] = pk[4]; p1.u4[1] = pk[5]; p1.u4[2] = pk[6]; p1.u4[3] = pk[7];

      // --- rescale + PV: O^T += V^T·P^T
      if (itl == 0) {
#pragma unroll
        for (int i = 0; i < 8; ++i) oac0.p[i] = oac0.p[i] * al2;
        __builtin_amdgcn_s_setprio(1);
        oac0.v = __builtin_amdgcn_mfma_f32_32x32x16_bf16(cv0, p0.s8, oac0.v, 0, 0, 0);
        oac0.v = __builtin_amdgcn_mfma_f32_32x32x16_bf16(cv1, p1.s8, oac0.v, 0, 0, 0);
        __builtin_amdgcn_s_setprio(0);
        m0 = m; l0 = l;
      } else {
#pragma unroll
        for (int i = 0; i < 8; ++i) oac1.p[i] = oac1.p[i] * al2;
        __builtin_amdgcn_s_setprio(1);
        oac1.v = __builtin_amdgcn_mfma_f32_32x32x16_bf16(cv0, p0.s8, oac1.v, 0, 0, 0);
        oac1.v = __builtin_amdgcn_mfma_f32_32x32x16_bf16(cv1, p1.s8, oac1.v, 0, 0, 0);
        __builtin_amdgcn_s_setprio(0);
        m1 = m; l1 = l;
      }
    }
  }

  // --- merge 4 j-splits x 2 its in LDS
#pragma unroll
  for (int itl = 0; itl < 2; ++itl) {
    float* om = OM + (size_t)((w * 2 + itl) * 32 + pl) * 36;
    const f32x16& oa = itl == 0 ? oac0.v : oac1.v;
#pragma unroll
    for (int g = 0; g < 4; ++g)  // d = (r&3) + 8g + 4h2
      *(float4*)&om[4 * h2 + 8 * g] =
          make_float4(oa[4 * g], oa[4 * g + 1], oa[4 * g + 2], oa[4 * g + 3]);
    if (h2 == 0) {
      ML[(w * 2 + itl) * 64 + pl] = itl == 0 ? m0 : m1;
      ML[(w * 2 + itl) * 64 + 32 + pl] = itl == 0 ? l0 : l1;
    }
  }
  __syncthreads();
  const int b = bh >> 2, h = bh & 3;
  float vals[8];
#pragma unroll
  for (int pass = 0; pass < 8; ++pass) {
    const int idx = tid + pass * 256;  // 2048 cells: [itl 2][i 32][d 32]
    const int itl = idx >> 10;
    const int i = (idx >> 5) & 31;
    const int d = idx & 31;
    float mk[4], lk[4];
#pragma unroll
    for (int k = 0; k < 4; ++k) {
      mk[k] = ML[(k * 2 + itl) * 64 + i];
      lk[k] = ML[(k * 2 + itl) * 64 + 32 + i];
    }
    const float M = fmaxf(fmaxf(mk[0], mk[1]), fmaxf(mk[2], mk[3]));
    float L = 0.f, V = 0.f;
#pragma unroll
    for (int k = 0; k < 4; ++k) {
      const float wk = EXP2F(mk[k] - M);
      L += lk[k] * wk;
      V += OM[((k * 2 + itl) * 32 + i) * 36 + d] * wk;
    }
    vals[pass] = V * (1.001953125f / L);  // (1+2^-9): P truncation bias comp
  }
  __syncthreads();  // all OM reads complete; safe to overlay

  // --- fused projection: out[ig][col] += sum_d vals[itl][i][d] * wout[h*32+d][col]
  float* V2 = OM;          // [2][32][32] = 2048 floats
  float* WL = OM + 2048;   // [32][64] = 2048 floats
#pragma unroll
  for (int pass = 0; pass < 8; ++pass) V2[tid + pass * 256] = vals[pass];
  {
    const float* wsrc = wout + (size_t)h * 32 * 64;
#pragma unroll
    for (int p = 0; p < 8; ++p) WL[tid + p * 256] = wsrc[tid + p * 256];
  }
  __syncthreads();
#pragma unroll
  for (int p = 0; p < 16; ++p) {
    const int idx = tid + p * 256;  // 4096 cells: [itl 2][i 32][col 64]
    const int itl = idx >> 11;
    const int i = (idx >> 6) & 31;
    const int col = idx & 63;
    float acc = 0.f;
#pragma unroll
    for (int d = 0; d < 32; ++d)
      acc = fmaf(V2[itl * 1024 + i * 32 + d], WL[d * 64 + col], acc);
    const int ig = (itp * 2 + itl) * 32 + i;
    atomicAdd(&out[((size_t)(b * 4096) + ig) * 64 + col], acc);
  }
}

// ---------------------------------------------------------------------------
extern "C" void kernel_launch(void* const* d_in, const int* in_sizes, int n_in,
                              void* d_out, int out_size, void* d_ws, size_t ws_size,
                              hipStream_t stream) {
  const float* input = (const float*)d_in[0];
  const float* w_qkv = (const float*)d_in[1];
  const float* w_out = (const float*)d_in[2];
  const float* b_out = (const float*)d_in[3];

  char* W = (char*)d_ws;
  float* qf = (float*)(W + 0);
  float* kf = (float*)(W + (4u << 20));
  ushort* kfr_hi = (ushort*)(W + (8u << 20));
  ushort* kfr_lo = (ushort*)(W + (10u << 20));
  ushort* vfr = (ushort*)(W + (12u << 20));
  float* psum = (float*)(W + (18u << 20));
  float* psq = (float*)(W + (18u << 20) + (128u << 10));
  float* out = (float*)d_out;

  hipLaunchKernelGGL(qkv_kernel, dim3(768), dim3(256), 0, stream, input, w_qkv, qf, kf,
                     vfr, psum, psq, b_out, out);
  hipLaunchKernelGGL(norm_kernel, dim3(128), dim3(256), 0, stream, kf, kfr_hi, kfr_lo,
                     psum, psq);
  hipLaunchKernelGGL(attn_kernel, dim3(512), dim3(256), 0, stream, qf, psum, psq,
                     kfr_hi, kfr_lo, vfr, w_out, out);
}

// Round 16
// 118.081 us; speedup vs baseline: 1.0455x; 1.0455x over previous
//
#include <hip/hip_runtime.h>
#include <math.h>
#include <stdint.h>

// B=2, S=4096, H=4, D=32, C=64. SCALE=16 folded as 16*log2(e) into q (base-2 softmax).
//
// ws layout (bytes):
//   0    : qf raw fp32 [8][4096][32]
//   8 MB : kfr_hi ushort frag-major [8][128 jt][2 c][64 lane][8]  (RAW k, sigma rows)
//   10 MB: kfr_lo ushort frag-major
//   12 MB: vfr    ushort frag-major [8][128 jt][2 c][64 lane][8]
//   18 MB: psum fp32 (128 KB), psq (128 KB)
//
// R4: qkv on MFMA (split-precision bf16 hh+hl+lh, ~2^-16 rel).
// R7: proj fused into attn epilogue (atomicAdd partials, qkv bias-inits out).
// R9: attn = 2 i-tiles/wave, 4 waves/block, grid 512 (best attn shape).
// R14: Q-norm in attn prologue (in-register frag build from raw qf).
// R15: norm_kernel ELIMINATED (3->2 kernels; each boundary ~12-15us measured
//     via R7). Algebra: K-norm commutes with softmax — S = (Qn*invK)^T @ K_raw
//     - u[i], u[i] const per softmax row -> cancels. qkv packs RAW K to
//     sigma-row frag-major hi/lo (VT path, like V); invK folds into attn's
//     Q affine (A = QSCALE*invQ*invK, B = -muQ*A). kf row-major dead.

typedef __attribute__((ext_vector_type(8))) short short8;
typedef __attribute__((ext_vector_type(2))) float f32x2;
typedef __attribute__((ext_vector_type(4))) float f32x4;
typedef __attribute__((ext_vector_type(16))) float f32x16;

#define QSCALE 23.083120654223414f /* 16 * log2(e) */

#if __has_builtin(__builtin_amdgcn_exp2f)
#define EXP2F(x) __builtin_amdgcn_exp2f(x)
#else
#define EXP2F(x) exp2f(x)
#endif

__device__ inline uint32_t pack_hilo(float y) {
  uint32_t uy = __float_as_uint(y);
  uint32_t hb = (uy + 0x7fffu + ((uy >> 16) & 1u)) >> 16;  // RNE bf16
  float hf = __uint_as_float(hb << 16);
  float r = y - hf;
  uint32_t ur = __float_as_uint(r);
  uint32_t lb = (ur + 0x7fffu + ((ur >> 16) & 1u)) >> 16;
  return (hb << 16) | (lb & 0xffffu);
}

__device__ inline ushort f32_to_bf16(float y) {
  uint32_t uy = __float_as_uint(y);
  return (ushort)((uy + 0x7fffu + ((uy >> 16) & 1u)) >> 16);
}

__device__ inline float bpermf(int addr, float v) {
  return __int_as_float(__builtin_amdgcn_ds_bpermute(addr, __float_as_int(v)));
}

__device__ inline short8 as_s8(uint4 v) {
  union { uint4 u; short8 s; } t;
  t.u = v;
  return t.s;
}

// ---------------------------------------------------------------------------
// Kernel 1 (R15): qkv = input @ w_qkv via 32x32x16 bf16 MFMA, split precision.
// q -> raw fp32 qf + stats; k -> RAW sigma-row frag-major hi/lo + stats (no kf);
// v -> frag-major bf16. Pre-fills out with bias (attn accumulates proj).
__global__ __launch_bounds__(256) void qkv_kernel(const float* __restrict__ in,
                                                  const float* __restrict__ w,
                                                  float* __restrict__ qf,
                                                  ushort* __restrict__ kfr_hi,
                                                  ushort* __restrict__ kfr_lo,
                                                  ushort* __restrict__ vfr,
                                                  float* __restrict__ psum,
                                                  float* __restrict__ psq,
                                                  const float* __restrict__ bias,
                                                  float* __restrict__ out) {
  __shared__ char smem[18432];  // Bh[64*72]u16 | Bl[64*72]u16; VT[64][68]f32 aliases after
  __shared__ float ssum[64], ssq[64];
  ushort* Bh = (ushort*)smem;
  ushort* Bl = (ushort*)(smem + 9216);
  float* VT = (float*)smem;  // 64*68*4 = 17408 <= 18432; used only after barrier

  const int ctile = blockIdx.x % 6;
  const int stile = blockIdx.x / 6;
  const int tid = threadIdx.x;
  const int row0 = stile * 64;
  const int sel = ctile >> 1;  // 0=q 1=k 2=v  (block-uniform)

  // bias-init of out (proj accumulator target); grid-stride, 8192*64 floats
  for (int i = blockIdx.x * 256 + tid; i < 8192 * 64; i += 768 * 256)
    out[i] = bias[i & 63];

  if (tid < 64) { ssum[tid] = 0.f; ssq[tid] = 0.f; }

  // ---- stage w^T hi/lo: thread: col = tid&63, k = (tid>>6)*16 .. +15
  {
    const int col = tid & 63;
    const int k0 = (tid >> 6) * 16;
    const float* wp = w + (size_t)k0 * 384 + ctile * 64 + col;
    float xv[16];
#pragma unroll
    for (int j = 0; j < 16; ++j) xv[j] = wp[(size_t)j * 384];
    uint32_t hi[8], lo[8];
#pragma unroll
    for (int p = 0; p < 8; ++p) {
      const uint32_t u0 = __float_as_uint(xv[2 * p]);
      const uint32_t u1 = __float_as_uint(xv[2 * p + 1]);
      hi[p] = __builtin_amdgcn_perm(u1, u0, 0x07060302u);
      const float d0 = xv[2 * p] - __uint_as_float(u0 & 0xffff0000u);
      const float d1 = xv[2 * p + 1] - __uint_as_float(u1 & 0xffff0000u);
      lo[p] = __builtin_amdgcn_perm(__float_as_uint(d1), __float_as_uint(d0), 0x07060302u);
    }
    uint4* bh = (uint4*)&Bh[col * 72 + k0];
    bh[0] = make_uint4(hi[0], hi[1], hi[2], hi[3]);
    bh[1] = make_uint4(hi[4], hi[5], hi[6], hi[7]);
    uint4* bl = (uint4*)&Bl[col * 72 + k0];
    bl[0] = make_uint4(lo[0], lo[1], lo[2], lo[3]);
    bl[1] = make_uint4(lo[4], lo[5], lo[6], lo[7]);
  }
  __syncthreads();

  const int wv = tid >> 6, lane = tid & 63;
  const int wr = wv >> 1, wc = wv & 1;
  const int h2 = lane >> 5, pl = lane & 31;

  // ---- A frags from global (in rows), trunc hi/lo
  short8 ah[4], al[4];
  {
    const float* ap = in + (size_t)(row0 + wr * 32 + pl) * 64 + h2 * 8;
#pragma unroll
    for (int kb = 0; kb < 4; ++kb) {
      const float4 xa = *(const float4*)(ap + kb * 16);
      const float4 xb = *(const float4*)(ap + kb * 16 + 4);
      const float xs[8] = {xa.x, xa.y, xa.z, xa.w, xb.x, xb.y, xb.z, xb.w};
      uint32_t hp[4], lp[4];
#pragma unroll
      for (int p = 0; p < 4; ++p) {
        const uint32_t u0 = __float_as_uint(xs[2 * p]);
        const uint32_t u1 = __float_as_uint(xs[2 * p + 1]);
        hp[p] = __builtin_amdgcn_perm(u1, u0, 0x07060302u);
        const float d0 = xs[2 * p] - __uint_as_float(u0 & 0xffff0000u);
        const float d1 = xs[2 * p + 1] - __uint_as_float(u1 & 0xffff0000u);
        lp[p] = __builtin_amdgcn_perm(__float_as_uint(d1), __float_as_uint(d0), 0x07060302u);
      }
      union { uint32_t u[4]; short8 s; } th, tl;
      th.u[0] = hp[0]; th.u[1] = hp[1]; th.u[2] = hp[2]; th.u[3] = hp[3];
      tl.u[0] = lp[0]; tl.u[1] = lp[1]; tl.u[2] = lp[2]; tl.u[3] = lp[3];
      ah[kb] = th.s;
      al[kb] = tl.s;
    }
  }

  // ---- B frags from LDS
  const ushort* bhp = &Bh[(wc * 32 + pl) * 72 + h2 * 8];
  const ushort* blp = &Bl[(wc * 32 + pl) * 72 + h2 * 8];
  f32x16 acc = {};
#pragma unroll
  for (int kb = 0; kb < 4; ++kb) {
    const short8 bh = *(const short8*)(bhp + kb * 16);
    const short8 bl = *(const short8*)(blp + kb * 16);
    acc = __builtin_amdgcn_mfma_f32_32x32x16_bf16(ah[kb], bh, acc, 0, 0, 0);
    acc = __builtin_amdgcn_mfma_f32_32x32x16_bf16(ah[kb], bl, acc, 0, 0, 0);
    acc = __builtin_amdgcn_mfma_f32_32x32x16_bf16(al[kb], bh, acc, 0, 0, 0);
  }

  const int b = row0 >> 12;
  const int sl0 = (row0 & 4095) + wr * 32;
  const int chg = ctile * 64 + wc * 32 + pl;
  const int jt0 = (row0 & 4095) >> 5;

  if (sel == 0) {
    // q: raw fp32 rows + stats
    const int hd0 = chg & 127;
    const int h = hd0 >> 5, d0 = hd0 & 31;
    float* dst = qf + ((size_t)(b * 4 + h) * 4096 + sl0) * 32 + d0;
    float s1 = 0.f, s2 = 0.f;
#pragma unroll
    for (int reg = 0; reg < 16; ++reg) {
      const int r = (reg & 3) + 8 * (reg >> 2) + 4 * h2;
      dst[(size_t)r * 32] = acc[reg];
      s1 += acc[reg];
      s2 += acc[reg] * acc[reg];
    }
    atomicAdd(&ssum[wc * 32 + pl], s1);
    atomicAdd(&ssq[wc * 32 + pl], s2);
    __syncthreads();
    if (tid < 64) {
      const int ch = (ctile & 1) * 64 + tid;
      const int idx = ((b * 128) + ch) * 64 + (stile & 63);
      psum[idx] = ssum[tid];
      psq[idx] = ssq[tid];
    }
  } else if (sel == 1) {
    // k: stats + VT transpose + RAW hi/lo sigma-row frag-major pack
    float s1 = 0.f, s2 = 0.f;
#pragma unroll
    for (int reg = 0; reg < 16; ++reg) {
      s1 += acc[reg];
      s2 += acc[reg] * acc[reg];
    }
    atomicAdd(&ssum[wc * 32 + pl], s1);
    atomicAdd(&ssq[wc * 32 + pl], s2);
    __syncthreads();  // ssum done AND Bh/Bl dead
    const int chv = wc * 32 + pl;
#pragma unroll
    for (int reg = 0; reg < 16; ++reg) {
      const int r = wr * 32 + (reg & 3) + 8 * (reg >> 2) + 4 * h2;
      VT[chv * 68 + r] = acc[reg];
    }
    __syncthreads();
    if (tid < 64) {
      const int ch = (ctile & 1) * 64 + tid;
      const int idx = (((2 + b) * 128) + ch) * 64 + (stile & 63);
      psum[idx] = ssum[tid];
      psq[idx] = ssq[tid];
    }
#pragma unroll
    for (int hl = 0; hl < 2; ++hl) {
      const int jtl = tid >> 7, c = (tid >> 6) & 1, ln = tid & 63;
      const int p = ln & 31, hh = ln >> 5;
      const int srow = 32 * jtl + ((p & 0x13) | ((p & 4) << 1) | ((p & 8) >> 1));
      const int dbase = hl * 32 + 16 * c + 8 * hh;
      uint32_t pk[8];
#pragma unroll
      for (int jj = 0; jj < 8; ++jj)
        pk[jj] = pack_hilo(VT[(dbase + jj) * 68 + srow]);
      uint4 HV, LV;
      HV.x = __builtin_amdgcn_perm(pk[1], pk[0], 0x07060302u);
      HV.y = __builtin_amdgcn_perm(pk[3], pk[2], 0x07060302u);
      HV.z = __builtin_amdgcn_perm(pk[5], pk[4], 0x07060302u);
      HV.w = __builtin_amdgcn_perm(pk[7], pk[6], 0x07060302u);
      LV.x = __builtin_amdgcn_perm(pk[1], pk[0], 0x05040100u);
      LV.y = __builtin_amdgcn_perm(pk[3], pk[2], 0x05040100u);
      LV.z = __builtin_amdgcn_perm(pk[5], pk[4], 0x05040100u);
      LV.w = __builtin_amdgcn_perm(pk[7], pk[6], 0x05040100u);
      const int h = (ctile - 2) * 2 + hl;
      const size_t doff =
          (((size_t)((b * 4 + h) * 128 + jt0 + jtl) * 2 + c) * 64 + ln) * 8;
      *(uint4*)(kfr_hi + doff) = HV;
      *(uint4*)(kfr_lo + doff) = LV;
    }
  } else {
    // v -> frag-major bf16 (truncation), via VT transpose
    __syncthreads();  // all waves done reading Bh/Bl
    const int chv = wc * 32 + pl;
#pragma unroll
    for (int reg = 0; reg < 16; ++reg) {
      const int r = wr * 32 + (reg & 3) + 8 * (reg >> 2) + 4 * h2;
      VT[chv * 68 + r] = acc[reg];
    }
    __syncthreads();
#pragma unroll
    for (int hl = 0; hl < 2; ++hl) {
      const int jtl = tid >> 7, c = (tid >> 6) & 1, ln = tid & 63;
      const int d = ln & 31, hh = ln >> 5;
      const int jloc = 32 * jtl + 16 * c + 8 * hh;
      const int ch = hl * 32 + d;
      const float4 f0 = *(const float4*)&VT[ch * 68 + jloc];
      const float4 f1 = *(const float4*)&VT[ch * 68 + jloc + 4];
      uint4 pk;
      pk.x = (uint32_t)f32_to_bf16(f0.x) | ((uint32_t)f32_to_bf16(f0.y) << 16);
      pk.y = (uint32_t)f32_to_bf16(f0.z) | ((uint32_t)f32_to_bf16(f0.w) << 16);
      pk.z = (uint32_t)f32_to_bf16(f1.x) | ((uint32_t)f32_to_bf16(f1.y) << 16);
      pk.w = (uint32_t)f32_to_bf16(f1.z) | ((uint32_t)f32_to_bf16(f1.w) << 16);
      const int h = (ctile - 4) * 2 + hl;
      ushort* dst =
          vfr + (((size_t)((b * 4 + h) * 128 + jt0 + jtl) * 2 + c) * 64 + ln) * 8;
      *(uint4*)dst = pk;
    }
  }
}

// ---------------------------------------------------------------------------
// Kernel 2 (R15): flash attention (2 i-tiles/wave) + Q/K-stats prologue +
// fused output projection. grid 512 (bh = bx&7, itp = bx>>3); block 256 = 4 wv.
// Prologue: reduce q-stats AND k-stats (OM scratch) -> A = QSCALE*invQ*invK,
// B = -muQ*A -> in-register Q frag build from raw qf. Main loop consumes RAW
// K frags (muK term cancels in row-softmax; invK folded into Q affine).
__global__ __launch_bounds__(256, 2) void attn_kernel(const float* __restrict__ qf,
                                                      const float* __restrict__ psum,
                                                      const float* __restrict__ psq,
                                                      const ushort* __restrict__ kfr_hi,
                                                      const ushort* __restrict__ kfr_lo,
                                                      const ushort* __restrict__ vfr,
                                                      const float* __restrict__ wout,
                                                      float* __restrict__ out) {
  __shared__ float OM[4 * 2 * 32 * 36];  // prologue scratch; merge buf; V2/WL
  __shared__ float ML[4 * 2 * 64];       // [wave][itl][ m[32] | l[32] ]
  __shared__ float tAB[64];              // A[32] | B[32]

  const int tid = threadIdx.x;
  const int w = tid >> 6;  // js = w, 4 j-splits
  const int lane = tid & 63;
  const int pl = lane & 31, h2 = lane >> 5;
  const int bh = blockIdx.x & 7;
  const int itp = blockIdx.x >> 3;

  // ---- stats prologue: q (tensor 0) and k (tensor 1) for this bh
  {
    const int d = tid >> 3, p = tid & 7;
    const int bq = ((bh >> 2) * 128 + (bh & 3) * 32 + d) * 64 + p * 8;
    const int bk = ((2 + (bh >> 2)) * 128 + (bh & 3) * 32 + d) * 64 + p * 8;
    float qs = 0.f, qq = 0.f, ks = 0.f, kq = 0.f;
#pragma unroll
    for (int e = 0; e < 8; ++e) {
      qs += psum[bq + e];
      qq += psq[bq + e];
      ks += psum[bk + e];
      kq += psq[bk + e];
    }
    OM[tid] = qs;
    OM[256 + tid] = qq;
    OM[512 + tid] = ks;
    OM[768 + tid] = kq;
  }
  __syncthreads();
  if (tid < 32) {
    float qs = 0.f, qq = 0.f, ks = 0.f, kq = 0.f;
#pragma unroll
    for (int e = 0; e < 8; ++e) {
      qs += OM[tid * 8 + e];
      qq += OM[256 + tid * 8 + e];
      ks += OM[512 + tid * 8 + e];
      kq += OM[768 + tid * 8 + e];
    }
    const float muQ = qs * (1.f / 4096.f);
    const float invQ = rsqrtf(qq * (1.f / 4096.f) - muQ * muQ + 1e-5f);
    const float muK = ks * (1.f / 4096.f);
    const float invK = rsqrtf(kq * (1.f / 4096.f) - muK * muK + 1e-5f);
    const float A = QSCALE * invQ * invK;
    tAB[tid] = A;
    tAB[32 + tid] = -muQ * A;
  }
  __syncthreads();

  // ---- build Q frags in-register from raw qf (both i-tiles, both c-halves)
  short8 qfrag_h[2][2], qfrag_l[2][2];  // [itl][c]
  {
    const float* qsrc = qf + (size_t)bh * 4096 * 32;
#pragma unroll
    for (int itl = 0; itl < 2; ++itl) {
      const int s = (itp * 2 + itl) * 32 + pl;
#pragma unroll
      for (int c = 0; c < 2; ++c) {
        const int d0 = 16 * c + 8 * h2;
        const float4 x0 = *(const float4*)&qsrc[(size_t)s * 32 + d0];
        const float4 x1 = *(const float4*)&qsrc[(size_t)s * 32 + d0 + 4];
        const float4 A0 = *(const float4*)&tAB[d0];
        const float4 A1 = *(const float4*)&tAB[d0 + 4];
        const float4 B0 = *(const float4*)&tAB[32 + d0];
        const float4 B1 = *(const float4*)&tAB[32 + d0 + 4];
        uint32_t pk[8];
        pk[0] = pack_hilo(fmaf(x0.x, A0.x, B0.x));
        pk[1] = pack_hilo(fmaf(x0.y, A0.y, B0.y));
        pk[2] = pack_hilo(fmaf(x0.z, A0.z, B0.z));
        pk[3] = pack_hilo(fmaf(x0.w, A0.w, B0.w));
        pk[4] = pack_hilo(fmaf(x1.x, A1.x, B1.x));
        pk[5] = pack_hilo(fmaf(x1.y, A1.y, B1.y));
        pk[6] = pack_hilo(fmaf(x1.z, A1.z, B1.z));
        pk[7] = pack_hilo(fmaf(x1.w, A1.w, B1.w));
        union { uint32_t u[4]; short8 s8; } hv, lv;
        hv.u[0] = __builtin_amdgcn_perm(pk[1], pk[0], 0x07060302u);
        hv.u[1] = __builtin_amdgcn_perm(pk[3], pk[2], 0x07060302u);
        hv.u[2] = __builtin_amdgcn_perm(pk[5], pk[4], 0x07060302u);
        hv.u[3] = __builtin_amdgcn_perm(pk[7], pk[6], 0x07060302u);
        lv.u[0] = __builtin_amdgcn_perm(pk[1], pk[0], 0x05040100u);
        lv.u[1] = __builtin_amdgcn_perm(pk[3], pk[2], 0x05040100u);
        lv.u[2] = __builtin_amdgcn_perm(pk[5], pk[4], 0x05040100u);
        lv.u[3] = __builtin_amdgcn_perm(pk[7], pk[6], 0x05040100u);
        qfrag_h[itl][c] = hv.s8;
        qfrag_l[itl][c] = lv.s8;
      }
    }
  }
  __syncthreads();  // OM scratch reads done

  const short8 qh0_0 = qfrag_h[0][0], qh1_0 = qfrag_h[0][1];
  const short8 ql0_0 = qfrag_l[0][0], ql1_0 = qfrag_l[0][1];
  const short8 qh0_1 = qfrag_h[1][0], qh1_1 = qfrag_h[1][1];
  const short8 ql0_1 = qfrag_l[1][0], ql1_1 = qfrag_l[1][1];

  const int bp32 = (lane ^ 32) << 2;

  const size_t kbase = (size_t)(bh * 128 + w * 32) * 1024 + lane * 8;
  const ushort* kh = kfr_hi + kbase;
  const ushort* kl = kfr_lo + kbase;
  const ushort* vp = vfr + kbase;

  union { f32x16 v; f32x2 p[8]; } oac0, oac1;
#pragma unroll
  for (int r = 0; r < 16; ++r) { oac0.v[r] = 0.f; oac1.v[r] = 0.f; }
  const f32x16 zf = {};  // persistent zero C operand
  float m0 = -INFINITY, l0 = 0.f, m1 = -INFINITY, l1 = 0.f;

  uint4 rk0 = *(const uint4*)(kh);
  uint4 rk1 = *(const uint4*)(kh + 512);
  uint4 rl0 = *(const uint4*)(kl);
  uint4 rl1 = *(const uint4*)(kl + 512);

  for (int t = 0; t < 32; ++t) {
    const short8 ck0 = as_s8(rk0), ck1 = as_s8(rk1);
    const short8 cl0 = as_s8(rl0), cl1 = as_s8(rl1);
    // V direct load for this iter (consumed at PV, ~400cy later)
    const uint4 rv0 = *(const uint4*)(vp + t * 1024);
    const uint4 rv1 = *(const uint4*)(vp + t * 1024 + 512);
    {  // K prefetch t+1 (last iter reads in-bounds adjacent ws region, unused)
      const int off = (t + 1) * 1024;
      rk0 = *(const uint4*)(kh + off);
      rk1 = *(const uint4*)(kh + off + 512);
      rl0 = *(const uint4*)(kl + off);
      rl1 = *(const uint4*)(kl + off + 512);
    }
    const short8 cv0 = as_s8(rv0), cv1 = as_s8(rv1);

#pragma unroll
    for (int itl = 0; itl < 2; ++itl) {
      const short8 qh0 = itl == 0 ? qh0_0 : qh0_1;
      const short8 qh1 = itl == 0 ? qh1_0 : qh1_1;
      const short8 ql0 = itl == 0 ? ql0_0 : ql0_1;
      const short8 ql1 = itl == 0 ? ql1_0 : ql1_1;
      float m = itl == 0 ? m0 : m1;
      float l = itl == 0 ? l0 : l1;

      // --- S^T = K·Q^T (A = raw-K sigma-rows, B = Q''), split precision
      __builtin_amdgcn_s_setprio(1);
      union { f32x16 v; f32x2 p[8]; } sc;
      sc.v = __builtin_amdgcn_mfma_f32_32x32x16_bf16(ck0, qh0, zf, 0, 0, 0);
      sc.v = __builtin_amdgcn_mfma_f32_32x32x16_bf16(ck1, qh1, sc.v, 0, 0, 0);
      sc.v = __builtin_amdgcn_mfma_f32_32x32x16_bf16(ck0, ql0, sc.v, 0, 0, 0);
      sc.v = __builtin_amdgcn_mfma_f32_32x32x16_bf16(ck1, ql1, sc.v, 0, 0, 0);
      sc.v = __builtin_amdgcn_mfma_f32_32x32x16_bf16(cl0, qh0, sc.v, 0, 0, 0);
      sc.v = __builtin_amdgcn_mfma_f32_32x32x16_bf16(cl1, qh1, sc.v, 0, 0, 0);
      __builtin_amdgcn_s_setprio(0);

      // --- online softmax (base-2); max via v_max3 tree
      const float x0 = fmaxf(fmaxf(sc.v[0], sc.v[1]), sc.v[2]);
      const float x1 = fmaxf(fmaxf(sc.v[3], sc.v[4]), sc.v[5]);
      const float x2 = fmaxf(fmaxf(sc.v[6], sc.v[7]), sc.v[8]);
      const float x3 = fmaxf(fmaxf(sc.v[9], sc.v[10]), sc.v[11]);
      const float x4 = fmaxf(fmaxf(sc.v[12], sc.v[13]), sc.v[14]);
      float mx = fmaxf(fmaxf(fmaxf(x0, x1), x2), fmaxf(fmaxf(x3, x4), sc.v[15]));
      mx = fmaxf(mx, bpermf(bp32, mx));
      const float mn = fmaxf(m, mx);
      const float al = EXP2F(m - mn);
      m = mn;
      const f32x2 mn2 = {mn, mn};
#pragma unroll
      for (int i = 0; i < 8; ++i) sc.p[i] = sc.p[i] - mn2;
#pragma unroll
      for (int r = 0; r < 16; ++r) sc.v[r] = EXP2F(sc.v[r]);
      const f32x2 a0 = sc.p[0] + sc.p[1], a1 = sc.p[2] + sc.p[3];
      const f32x2 a2 = sc.p[4] + sc.p[5], a3 = sc.p[6] + sc.p[7];
      const f32x2 b0 = a0 + a1, b1 = a2 + a3;
      const f32x2 c0 = b0 + b1;
      float rs = c0.x + c0.y;
      rs += bpermf(bp32, rs);
      l = l * al + rs;
      const f32x2 al2 = {al, al};

      // --- P -> bf16 (truncation; bias comp in merge)
      uint32_t pk[8];
#pragma unroll
      for (int i = 0; i < 8; ++i)
        pk[i] = __builtin_amdgcn_perm(__float_as_uint(sc.v[2 * i + 1]),
                                      __float_as_uint(sc.v[2 * i]), 0x07060302u);
      union { uint32_t u4[4]; short8 s8; } p0, p1;
      p0.u4[0] = pk[0]; p0.u4[1] = pk[1]; p0.u4[2] = pk[2]; p0.u4[3] = pk[3];
      p1.u4[0] = pk[4]; p1.u4[1] = pk[5]; p1.u4[2] = pk[6]; p1.u4[3] = pk[7];

      // --- rescale + PV: O^T += V^T·P^T
      if (itl == 0) {
#pragma unroll
        for (int i = 0; i < 8; ++i) oac0.p[i] = oac0.p[i] * al2;
        __builtin_amdgcn_s_setprio(1);
        oac0.v = __builtin_amdgcn_mfma_f32_32x32x16_bf16(cv0, p0.s8, oac0.v, 0, 0, 0);
        oac0.v = __builtin_amdgcn_mfma_f32_32x32x16_bf16(cv1, p1.s8, oac0.v, 0, 0, 0);
        __builtin_amdgcn_s_setprio(0);
        m0 = m; l0 = l;
      } else {
#pragma unroll
        for (int i = 0; i < 8; ++i) oac1.p[i] = oac1.p[i] * al2;
        __builtin_amdgcn_s_setprio(1);
        oac1.v = __builtin_amdgcn_mfma_f32_32x32x16_bf16(cv0, p0.s8, oac1.v, 0, 0, 0);
        oac1.v = __builtin_amdgcn_mfma_f32_32x32x16_bf16(cv1, p1.s8, oac1.v, 0, 0, 0);
        __builtin_amdgcn_s_setprio(0);
        m1 = m; l1 = l;
      }
    }
  }

  __syncthreads();  // OM free (prologue long done); reuse for merge
  // --- merge 4 j-splits x 2 its in LDS
#pragma unroll
  for (int itl = 0; itl < 2; ++itl) {
    float* om = OM + (size_t)((w * 2 + itl) * 32 + pl) * 36;
    const f32x16& oa = itl == 0 ? oac0.v : oac1.v;
#pragma unroll
    for (int g = 0; g < 4; ++g)  // d = (r&3) + 8g + 4h2
      *(float4*)&om[4 * h2 + 8 * g] =
          make_float4(oa[4 * g], oa[4 * g + 1], oa[4 * g + 2], oa[4 * g + 3]);
    if (h2 == 0) {
      ML[(w * 2 + itl) * 64 + pl] = itl == 0 ? m0 : m1;
      ML[(w * 2 + itl) * 64 + 32 + pl] = itl == 0 ? l0 : l1;
    }
  }
  __syncthreads();
  const int b = bh >> 2, h = bh & 3;
  float vals[8];
#pragma unroll
  for (int pass = 0; pass < 8; ++pass) {
    const int idx = tid + pass * 256;  // 2048 cells: [itl 2][i 32][d 32]
    const int itl = idx >> 10;
    const int i = (idx >> 5) & 31;
    const int d = idx & 31;
    float mk[4], lk[4];
#pragma unroll
    for (int k = 0; k < 4; ++k) {
      mk[k] = ML[(k * 2 + itl) * 64 + i];
      lk[k] = ML[(k * 2 + itl) * 64 + 32 + i];
    }
    const float M = fmaxf(fmaxf(mk[0], mk[1]), fmaxf(mk[2], mk[3]));
    float L = 0.f, V = 0.f;
#pragma unroll
    for (int k = 0; k < 4; ++k) {
      const float wk = EXP2F(mk[k] - M);
      L += lk[k] * wk;
      V += OM[((k * 2 + itl) * 32 + i) * 36 + d] * wk;
    }
    vals[pass] = V * (1.001953125f / L);  // (1+2^-9): P truncation bias comp
  }
  __syncthreads();  // all OM reads complete; safe to overlay

  // --- fused projection: out[ig][col] += sum_d vals[itl][i][d] * wout[h*32+d][col]
  float* V2 = OM;          // [2][32][32] = 2048 floats
  float* WL = OM + 2048;   // [32][64] = 2048 floats
#pragma unroll
  for (int pass = 0; pass < 8; ++pass) V2[tid + pass * 256] = vals[pass];
  {
    const float* wsrc = wout + (size_t)h * 32 * 64;
#pragma unroll
    for (int p = 0; p < 8; ++p) WL[tid + p * 256] = wsrc[tid + p * 256];
  }
  __syncthreads();
#pragma unroll
  for (int p = 0; p < 16; ++p) {
    const int idx = tid + p * 256;  // 4096 cells: [itl 2][i 32][col 64]
    const int itl = idx >> 11;
    const int i = (idx >> 6) & 31;
    const int col = idx & 63;
    float acc = 0.f;
#pragma unroll
    for (int d = 0; d < 32; ++d)
      acc = fmaf(V2[itl * 1024 + i * 32 + d], WL[d * 64 + col], acc);
    const int ig = (itp * 2 + itl) * 32 + i;
    atomicAdd(&out[((size_t)(b * 4096) + ig) * 64 + col], acc);
  }
}

// ---------------------------------------------------------------------------
extern "C" void kernel_launch(void* const* d_in, const int* in_sizes, int n_in,
                              void* d_out, int out_size, void* d_ws, size_t ws_size,
                              hipStream_t stream) {
  const float* input = (const float*)d_in[0];
  const float* w_qkv = (const float*)d_in[1];
  const float* w_out = (const float*)d_in[2];
  const float* b_out = (const float*)d_in[3];

  char* W = (char*)d_ws;
  float* qf = (float*)(W + 0);
  ushort* kfr_hi = (ushort*)(W + (8u << 20));
  ushort* kfr_lo = (ushort*)(W + (10u << 20));
  ushort* vfr = (ushort*)(W + (12u << 20));
  float* psum = (float*)(W + (18u << 20));
  float* psq = (float*)(W + (18u << 20) + (128u << 10));
  float* out = (float*)d_out;

  hipLaunchKernelGGL(qkv_kernel, dim3(768), dim3(256), 0, stream, input, w_qkv, qf,
                     kfr_hi, kfr_lo, vfr, psum, psq, b_out, out);
  hipLaunchKernelGGL(attn_kernel, dim3(512), dim3(256), 0, stream, qf, psum, psq,
                     kfr_hi, kfr_lo, vfr, w_out, out);
}